// Round 13
// baseline (163.853 us; speedup 1.0000x reference)
//
#include <hip/hip_runtime.h>

constexpr int Bn  = 1024;
constexpr int Tn  = 8192;
constexpr int Wn  = 2048;   // NUM_WORDS
constexpr int TPB = 256;
constexpr int NW  = TPB / 64;         // 4 waves per block
constexpr int EPT = 4;                // elements per thread
constexpr int SEG = TPB * EPT;        // 1024 elements per block
constexpr int BPR = Tn / SEG;         // 8 blocks per row
static_assert(BPR == 8, "blockIdx decode uses >>3 / &7");
// All loss terms are (log-difference)^2; compute in log2, fold ln(2)^2 into weights.
constexpr float LN2S = 0.4804530139182014f;   // ln(2)^2
// fold wd into the per-block weighted scalar: 0.3*wd/(Bn*(Wn-1)) == WDC*wd/(Bn*Tn)
constexpr float WDC = 0.3f * (float)Tn / (float)(Wn - 1);

// Lean rule evaluation (algebraically identical to the reference; see R11).
__device__ __forceinline__ void rule_eval2(float dp, float dpn, int tok, bool valid_next,
                                           float& gg, float& sa) {
  const bool t27 = (tok == 27), t43 = (tok == 43);
  const bool in_init = (tok == 94) | (tok == 122) | (tok == 100) | (tok == 92) | t43 | t27;
  const float expected = (tok == 122) ? 3.f : ((t43 | t27) ? 5.f : 2.f);
  const float t1 = dp - expected;
  const bool fire1 = in_init && (t1 > 0.f);
  const float g1 = fire1 ? t1 : 0.f;
  const bool in_ratio = (tok == 44) | (tok == 28) | (tok == 29) | t27 | (tok == 121) | t43;
  const bool fire2 = in_ratio && valid_next && (3.f * dp > dpn);
  const float g2 = fire2 ? (dp - dpn * (1.f / 3.f)) : 0.f;
  gg = g1 + g2;
  sa = fire2 ? g2 : g1;
}

__device__ __forceinline__ float wave_reduce(float v) {
  #pragma unroll
  for (int o = 32; o > 0; o >>= 1) v += __shfl_down(v, o, 64);
  return v;
}

// R8's block config (256 threads, 4-wave barriers, 8 blocks/row — best measured
// kernel time) + rule_eval2 + log2 folding.
__global__ __launch_bounds__(TPB, 6) void loss_kernel(
    const float* __restrict__ dur_pred, const float* __restrict__ dur_gt,
    const int* __restrict__ ph2word, const int* __restrict__ txt,
    float4* __restrict__ partials)
{
  __shared__ int   hk[NW];                 // head key (k0 of lane 0) per wave
  __shared__ float ndp0[NW], ndp1[NW];     // lane0's dp4.x/.y (rule neighbor handoff)
  __shared__ int   ntk[NW];                // lane0's tk4.x
  __shared__ int   twk[NW];                // wave tail-run key
  __shared__ float twp[NW], twg[NW];       // wave tail-run in-wave sums
  __shared__ int   wu_[NW];                // wave is entirely one open run
  __shared__ float bnd[4];                 // {wf_p, wf_g, wl_p, wl_g}
  __shared__ int   smeta[2];               // {wf, wl}
  __shared__ float red[NW][3];             // {x, sp_wave, sg_wave}

  const int row = blockIdx.x >> 3;
  const int sub = blockIdx.x & 7;
  const int s = sub * SEG;
  const size_t roff = (size_t)row * Tn;
  const float* __restrict__ dpr = dur_pred + roff;
  const float* __restrict__ dgr = dur_gt + roff;
  const int*   __restrict__ pwr = ph2word + roff;
  const int*   __restrict__ tkr = txt + roff;

  const int tid  = threadIdx.x;
  const int lane = tid & 63;
  const int wid  = tid >> 6;
  const bool is63 = (lane == 63);
  const int base = s + tid * EPT;

  // ---- load phase ----
  float4 dp4 = *reinterpret_cast<const float4*>(dpr + base);
  float4 dg4 = *reinterpret_cast<const float4*>(dgr + base);
  int4   pw4 = *reinterpret_cast<const int4*>(pwr + base);
  int4   tk4 = *reinterpret_cast<const int4*>(tkr + base);

  // block-last thread: rule-neighbor comes from the next block's region
  float nb_dp = 0.f, nb_dp1 = 0.f; int nb_tk = -1;
  if (tid == TPB - 1) {
    const int p = base + EPT;
    if (p < Tn) { nb_dp = dpr[p]; nb_dp1 = dpr[p + 1]; nb_tk = tkr[p]; }
  }

  const int k0 = pw4.x, k1 = pw4.y, k2 = pw4.z, k3 = pw4.w;
  const float p0 = fmaxf(dp4.x, 0.f), p1 = fmaxf(dp4.y, 0.f),
              p2 = fmaxf(dp4.z, 0.f), p3 = fmaxf(dp4.w, 0.f);
  const float g0 = dg4.x, g1_ = dg4.y, g2_ = dg4.z, g3_ = dg4.w;
  const float Sp = p0 + p1 + p2 + p3;
  const float Sg = g0 + g1_ + g2_ + g3_;

  // trailing-run partial sums within this thread (elements with key == k3)
  float t3p = p3, t3g = g3_;
  if (k2 == k3) { t3p += p2; t3g += g2_;
    if (k1 == k3) { t3p += p1; t3g += g1_;
      if (k0 == k3) { t3p += p0; t3g += g0; } } }

  // inclusive prefix scans of full-thread sums (lane63 -> wave sp/sg for free)
  float Pp = Sp, Pg = Sg;
  #pragma unroll
  for (int o = 1; o < 64; o <<= 1) {
    float tp = __shfl_up(Pp, o, 64);
    float tg = __shfl_up(Pg, o, 64);
    if (lane >= o) { Pp += tp; Pg += tg; }
  }

  // carry-in for the run containing my element 0
  const int nk0 = __shfl_down(k0, 1, 64);        // lanes 0..62 valid
  const bool uni = (k0 == k3);
  const bool cn  = uni && (k3 == nk0);           // continues into next lane
  const unsigned long long cmask = __ballot(cn);
  const unsigned long long below = (1ull << lane) - 1ull;
  const unsigned long long y = (~cmask) & below;
  const int L = y ? (64 - __clzll(y)) : 0;       // first lane of my carry range
  const int Lm1 = (L > 0) ? (L - 1) : 0;
  const float Ppm1 = __shfl_up(Pp, 1, 64);
  const float Pgm1 = __shfl_up(Pg, 1, 64);
  const float PpL = __shfl(Pp, Lm1, 64);
  const float PgL = __shfl(Pg, Lm1, 64);
  const int   k3L = __shfl(k3, Lm1, 64);
  const float tpL = __shfl(t3p, Lm1, 64);
  const float tgL = __shfl(t3g, Lm1, 64);
  float Cp = 0.f, Cg = 0.f;
  if (L < lane) {                                 // full uniform threads [L, lane-1]
    Cp = Ppm1 - (L > 0 ? PpL : 0.f);
    Cg = Pgm1 - (L > 0 ? PgL : 0.f);
  }
  if (L > 0 && k3L == k0) {                       // partial tail of thread L-1
    Cp += tpL; Cg += tgL;
  }
  const bool open = (y == 0);                     // run chains to wave start

  // rules j=0..2 (in-register neighbors)
  float gg0, sa0, gg1, sa1, gg2, sa2, gg3, sa3;
  rule_eval2(dp4.x, dp4.y, tk4.x, true, gg0, sa0);
  rule_eval2(dp4.y, dp4.z, tk4.y, true, gg1, sa1);
  rule_eval2(dp4.z, dp4.w, tk4.z, true, gg2, sa2);
  float dpn3 = __shfl_down(dp4.x, 1, 64);
  float ggn  = __shfl_down(gg0,  1, 64);

  // ---- LDS metadata ----
  if (lane == 0) { hk[wid] = k0; ndp0[wid] = dp4.x; ndp1[wid] = dp4.y; ntk[wid] = tk4.x; }
  if (is63) {
    twk[wid] = k3;
    twp[wid] = uni ? (Cp + Sp) : t3p;
    twg[wid] = uni ? (Cg + Sg) : t3g;
    wu_[wid] = (uni && open) ? 1 : 0;
  }
  if (tid == 0) { smeta[0] = k0; bnd[0] = 0.f; bnd[1] = 0.f; bnd[2] = 0.f; bnd[3] = 0.f; }
  if (tid == TPB - 1) smeta[1] = k3;
  __syncthreads();

  // cross-wave carry (wave-uniform walk, <=NW-1 steps)
  {
    const int myh = hk[wid];
    float Wp = 0.f, Wg = 0.f;
    for (int u = wid - 1; u >= 0; --u) {
      if (twk[u] != myh) break;
      Wp += twp[u]; Wg += twg[u];
      if (!wu_[u]) break;
    }
    if (open) { Cp += Wp; Cg += Wg; }
  }

  // lane-63 rule neighbor: LDS handoff from next wave (block-last: own loads)
  if (is63) {
    float a0, a1; int t0;
    if (tid == TPB - 1) { a0 = nb_dp; a1 = nb_dp1; t0 = nb_tk; }
    else                { a0 = ndp0[wid + 1]; a1 = ndp1[wid + 1]; t0 = ntk[wid + 1]; }
    float ng, ns_;
    rule_eval2(a0, a1, t0, base + EPT < Tn - 1, ng, ns_);
    dpn3 = a0; ggn = ng;
  }
  rule_eval2(dp4.w, dpn3, tk4.w, base + 3 < Tn - 1, gg3, sa3);

  // pdur + rules losses (log2-space)
  const float dpx[4] = {dp4.x, dp4.y, dp4.z, dp4.w};
  const float dgl[4] = {g0, g1_, g2_, g3_};
  const float sav[4] = {sa0, sa1, sa2, sa3};
  const float addv[4] = {gg1, gg2, gg3, (base + 3 < Tn - 1) ? ggn : 0.f};
  float pdur_s = 0.f, rules_s = 0.f;
  #pragma unroll
  for (int j = 0; j < 4; ++j) {
    float dp = dpx[j];
    float dr = dp - sav[j] + addv[j];
    float lp = __log2f(dp + 1.f);
    float dlr = lp - __log2f(dr + 1.f);
    rules_s += dlr * dlr;
    float dlg = lp - __log2f(dgl[j] + 1.f);
    pdur_s += dlg * dlg;
  }

  // run-compress with carry; owner thread finalizes each completed word
  const int wf = smeta[0], wl = smeta[1];
  const int nk_true = is63 ? ((tid == TPB - 1) ? -1 : hk[wid + 1]) : nk0;
  float wd_s = 0.f;
  {
    const int   kk[4] = {k0, k1, k2, k3};
    const float pp[4] = {p0, p1, p2, p3};
    const float gg[4] = {g0, g1_, g2_, g3_};
    int cur = k0; float ap = Cp, ag = Cg;
    #pragma unroll
    for (int j = 0; j < 4; ++j) {
      if (kk[j] != cur) {
        if (cur == wl)      { bnd[2] = ap; bnd[3] = ag; }   // unique writer
        else if (cur == wf) { bnd[0] = ap; bnd[1] = ag; }   // unique writer
        else { float d = __log2f(ap + 1.f) - __log2f(ag + 1.f); wd_s += d * d; }
        cur = kk[j]; ap = 0.f; ag = 0.f;
      }
      ap += pp[j]; ag += gg[j];
    }
    if (nk_true != cur) {            // run ends at my last element -> I own it
      if (cur == wl)      { bnd[2] = ap; bnd[3] = ag; }
      else if (cur == wf) { bnd[0] = ap; bnd[1] = ag; }
      else { float d = __log2f(ap + 1.f) - __log2f(ag + 1.f); wd_s += d * d; }
    }
  }

  // single weighted reduction (weights carry the ln2^2 factor)
  float x = (0.6f * LN2S) * pdur_s + (0.3f * LN2S) * rules_s + (WDC * LN2S) * wd_s;
  x = wave_reduce(x);
  if (lane == 0) red[wid][0] = x;
  if (is63) { red[wid][1] = Pp; red[wid][2] = Pg; }
  __syncthreads();

  if (tid == 0) {
    float xs = 0.f, sp = 0.f, sg = 0.f;
    #pragma unroll
    for (int w = 0; w < NW; ++w) { xs += red[w][0]; sp += red[w][1]; sg += red[w][2]; }
    float4 a, b, c;
    a.x = xs; a.y = sp; a.z = sg; a.w = 0.f;
    const bool single = (wf == wl);
    b.x = bnd[0]; b.y = bnd[1]; b.z = __int_as_float(single ? -1 : wf); b.w = 0.f;
    c.x = bnd[2]; c.y = bnd[3]; c.z = __int_as_float(wl); c.w = 0.f;
    const size_t idx = (size_t)blockIdx.x * 3;
    partials[idx]     = a;
    partials[idx + 1] = b;
    partials[idx + 2] = c;
  }
}

// One block: thread r folds row r's BPR partials. All 24 float4 loads hoisted
// ABOVE the serial merge chain so they issue concurrently.
__global__ __launch_bounds__(1024) void finalize_kernel(
    const float4* __restrict__ partials, float* __restrict__ out)
{
  __shared__ double wsum[16];
  const int r = threadIdx.x;            // one row per thread
  float4 A[BPR], Bv[BPR], Cv[BPR];
  #pragma unroll
  for (int j = 0; j < BPR; ++j) {
    const size_t idx = ((size_t)r * BPR + j) * 3;
    A[j]  = partials[idx];
    Bv[j] = partials[idx + 1];
    Cv[j] = partials[idx + 2];
  }

  double xs = 0.0, wdb = 0.0;
  float sp = 0.f, sg = 0.f;
  int curid = -1; float cp = 0.f, cg = 0.f;
  #pragma unroll
  for (int j = 0; j < BPR; ++j) {
    xs += (double)A[j].x; sp += A[j].y; sg += A[j].z;
    const int wfi = __float_as_int(Bv[j].z);
    const int wla = __float_as_int(Cv[j].z);
    if (wfi >= 0) {
      if (wfi != curid) {
        if (curid > 0) { float d = __log2f(cp + 1.f) - __log2f(cg + 1.f); wdb += (double)(d * d); }
        curid = wfi; cp = 0.f; cg = 0.f;
      }
      cp += Bv[j].x; cg += Bv[j].y;
    }
    if (wla >= 0) {
      if (wla != curid) {
        if (curid > 0) { float d = __log2f(cp + 1.f) - __log2f(cg + 1.f); wdb += (double)(d * d); }
        curid = wla; cp = 0.f; cg = 0.f;
      }
      cp += Cv[j].x; cg += Cv[j].y;
    }
  }
  if (curid > 0) { float d = __log2f(cp + 1.f) - __log2f(cg + 1.f); wdb += (double)(d * d); }

  float ds = __log2f(sp + 1.f) - __log2f(sg + 1.f);
  double contrib = xs / ((double)Bn * (double)Tn)
                 + (0.3 * (double)LN2S) * wdb / ((double)Bn * (double)(Wn - 1))
                 + (0.1 * (double)LN2S) * (double)(ds * ds) / (double)Bn;

  #pragma unroll
  for (int o = 32; o > 0; o >>= 1) contrib += __shfl_down(contrib, o, 64);
  if ((threadIdx.x & 63) == 0) wsum[threadIdx.x >> 6] = contrib;
  __syncthreads();
  if (threadIdx.x == 0) {
    double t = 0.0;
    #pragma unroll
    for (int i = 0; i < 16; ++i) t += wsum[i];
    out[0] = (float)t;
  }
}

extern "C" void kernel_launch(void* const* d_in, const int* in_sizes, int n_in,
                              void* d_out, int out_size, void* d_ws, size_t ws_size,
                              hipStream_t stream) {
  const float* dur_pred = (const float*)d_in[0];
  const float* dur_gt   = (const float*)d_in[1];
  const int*   ph2word  = (const int*)d_in[2];
  const int*   txt      = (const int*)d_in[3];

  // workspace: 8192 blocks x 48 B = 384 KB, fully overwritten (no memset)
  float4* partials = (float4*)d_ws;

  loss_kernel<<<Bn * BPR, TPB, 0, stream>>>(dur_pred, dur_gt, ph2word, txt, partials);
  finalize_kernel<<<1, 1024, 0, stream>>>(partials, (float*)d_out);
}

// Round 14
// 155.190 us; speedup vs baseline: 1.0558x; 1.0558x over previous
//
#include <hip/hip_runtime.h>

constexpr int Bn  = 1024;
constexpr int Tn  = 8192;
constexpr int Wn  = 2048;   // NUM_WORDS
constexpr int TPB = 256;
constexpr int NW  = TPB / 64;         // 4 waves per block
constexpr int EPT = 4;                // elements per thread
constexpr int SEG = TPB * EPT;        // 1024 elements per block
constexpr int BPR = Tn / SEG;         // 8 blocks per row
static_assert(BPR == 8, "blockIdx decode uses >>3 / &7");
// All loss terms are (log-difference)^2; compute in log2, fold ln(2)^2 into weights.
constexpr float LN2S = 0.4804530139182014f;   // ln(2)^2
// fold wd into the per-block weighted scalar: 0.3*wd/(Bn*(Wn-1)) == WDC*wd/(Bn*Tn)
constexpr float WDC = 0.3f * (float)Tn / (float)(Wn - 1);

// Lean rule evaluation (algebraically identical to the reference; see R11).
__device__ __forceinline__ void rule_eval2(float dp, float dpn, int tok, bool valid_next,
                                           float& gg, float& sa) {
  const bool t27 = (tok == 27), t43 = (tok == 43);
  const bool in_init = (tok == 94) | (tok == 122) | (tok == 100) | (tok == 92) | t43 | t27;
  const float expected = (tok == 122) ? 3.f : ((t43 | t27) ? 5.f : 2.f);
  const float t1 = dp - expected;
  const bool fire1 = in_init && (t1 > 0.f);
  const float g1 = fire1 ? t1 : 0.f;
  const bool in_ratio = (tok == 44) | (tok == 28) | (tok == 29) | t27 | (tok == 121) | t43;
  const bool fire2 = in_ratio && valid_next && (3.f * dp > dpn);
  const float g2 = fire2 ? (dp - dpn * (1.f / 3.f)) : 0.f;
  gg = g1 + g2;
  sa = fire2 ? g2 : g1;
}

__device__ __forceinline__ float wave_reduce(float v) {
  #pragma unroll
  for (int o = 32; o > 0; o >>= 1) v += __shfl_down(v, o, 64);
  return v;
}

// R13 loss_kernel, byte-identical (best measured: 43-45 us, absmax 0).
__global__ __launch_bounds__(TPB, 6) void loss_kernel(
    const float* __restrict__ dur_pred, const float* __restrict__ dur_gt,
    const int* __restrict__ ph2word, const int* __restrict__ txt,
    float4* __restrict__ partials)
{
  __shared__ int   hk[NW];                 // head key (k0 of lane 0) per wave
  __shared__ float ndp0[NW], ndp1[NW];     // lane0's dp4.x/.y (rule neighbor handoff)
  __shared__ int   ntk[NW];                // lane0's tk4.x
  __shared__ int   twk[NW];                // wave tail-run key
  __shared__ float twp[NW], twg[NW];       // wave tail-run in-wave sums
  __shared__ int   wu_[NW];                // wave is entirely one open run
  __shared__ float bnd[4];                 // {wf_p, wf_g, wl_p, wl_g}
  __shared__ int   smeta[2];               // {wf, wl}
  __shared__ float red[NW][3];             // {x, sp_wave, sg_wave}

  const int row = blockIdx.x >> 3;
  const int sub = blockIdx.x & 7;
  const int s = sub * SEG;
  const size_t roff = (size_t)row * Tn;
  const float* __restrict__ dpr = dur_pred + roff;
  const float* __restrict__ dgr = dur_gt + roff;
  const int*   __restrict__ pwr = ph2word + roff;
  const int*   __restrict__ tkr = txt + roff;

  const int tid  = threadIdx.x;
  const int lane = tid & 63;
  const int wid  = tid >> 6;
  const bool is63 = (lane == 63);
  const int base = s + tid * EPT;

  // ---- load phase ----
  float4 dp4 = *reinterpret_cast<const float4*>(dpr + base);
  float4 dg4 = *reinterpret_cast<const float4*>(dgr + base);
  int4   pw4 = *reinterpret_cast<const int4*>(pwr + base);
  int4   tk4 = *reinterpret_cast<const int4*>(tkr + base);

  // block-last thread: rule-neighbor comes from the next block's region
  float nb_dp = 0.f, nb_dp1 = 0.f; int nb_tk = -1;
  if (tid == TPB - 1) {
    const int p = base + EPT;
    if (p < Tn) { nb_dp = dpr[p]; nb_dp1 = dpr[p + 1]; nb_tk = tkr[p]; }
  }

  const int k0 = pw4.x, k1 = pw4.y, k2 = pw4.z, k3 = pw4.w;
  const float p0 = fmaxf(dp4.x, 0.f), p1 = fmaxf(dp4.y, 0.f),
              p2 = fmaxf(dp4.z, 0.f), p3 = fmaxf(dp4.w, 0.f);
  const float g0 = dg4.x, g1_ = dg4.y, g2_ = dg4.z, g3_ = dg4.w;
  const float Sp = p0 + p1 + p2 + p3;
  const float Sg = g0 + g1_ + g2_ + g3_;

  // trailing-run partial sums within this thread (elements with key == k3)
  float t3p = p3, t3g = g3_;
  if (k2 == k3) { t3p += p2; t3g += g2_;
    if (k1 == k3) { t3p += p1; t3g += g1_;
      if (k0 == k3) { t3p += p0; t3g += g0; } } }

  // inclusive prefix scans of full-thread sums (lane63 -> wave sp/sg for free)
  float Pp = Sp, Pg = Sg;
  #pragma unroll
  for (int o = 1; o < 64; o <<= 1) {
    float tp = __shfl_up(Pp, o, 64);
    float tg = __shfl_up(Pg, o, 64);
    if (lane >= o) { Pp += tp; Pg += tg; }
  }

  // carry-in for the run containing my element 0
  const int nk0 = __shfl_down(k0, 1, 64);        // lanes 0..62 valid
  const bool uni = (k0 == k3);
  const bool cn  = uni && (k3 == nk0);           // continues into next lane
  const unsigned long long cmask = __ballot(cn);
  const unsigned long long below = (1ull << lane) - 1ull;
  const unsigned long long y = (~cmask) & below;
  const int L = y ? (64 - __clzll(y)) : 0;       // first lane of my carry range
  const int Lm1 = (L > 0) ? (L - 1) : 0;
  const float Ppm1 = __shfl_up(Pp, 1, 64);
  const float Pgm1 = __shfl_up(Pg, 1, 64);
  const float PpL = __shfl(Pp, Lm1, 64);
  const float PgL = __shfl(Pg, Lm1, 64);
  const int   k3L = __shfl(k3, Lm1, 64);
  const float tpL = __shfl(t3p, Lm1, 64);
  const float tgL = __shfl(t3g, Lm1, 64);
  float Cp = 0.f, Cg = 0.f;
  if (L < lane) {                                 // full uniform threads [L, lane-1]
    Cp = Ppm1 - (L > 0 ? PpL : 0.f);
    Cg = Pgm1 - (L > 0 ? PgL : 0.f);
  }
  if (L > 0 && k3L == k0) {                       // partial tail of thread L-1
    Cp += tpL; Cg += tgL;
  }
  const bool open = (y == 0);                     // run chains to wave start

  // rules j=0..2 (in-register neighbors)
  float gg0, sa0, gg1, sa1, gg2, sa2, gg3, sa3;
  rule_eval2(dp4.x, dp4.y, tk4.x, true, gg0, sa0);
  rule_eval2(dp4.y, dp4.z, tk4.y, true, gg1, sa1);
  rule_eval2(dp4.z, dp4.w, tk4.z, true, gg2, sa2);
  float dpn3 = __shfl_down(dp4.x, 1, 64);
  float ggn  = __shfl_down(gg0,  1, 64);

  // ---- LDS metadata ----
  if (lane == 0) { hk[wid] = k0; ndp0[wid] = dp4.x; ndp1[wid] = dp4.y; ntk[wid] = tk4.x; }
  if (is63) {
    twk[wid] = k3;
    twp[wid] = uni ? (Cp + Sp) : t3p;
    twg[wid] = uni ? (Cg + Sg) : t3g;
    wu_[wid] = (uni && open) ? 1 : 0;
  }
  if (tid == 0) { smeta[0] = k0; bnd[0] = 0.f; bnd[1] = 0.f; bnd[2] = 0.f; bnd[3] = 0.f; }
  if (tid == TPB - 1) smeta[1] = k3;
  __syncthreads();

  // cross-wave carry (wave-uniform walk, <=NW-1 steps)
  {
    const int myh = hk[wid];
    float Wp = 0.f, Wg = 0.f;
    for (int u = wid - 1; u >= 0; --u) {
      if (twk[u] != myh) break;
      Wp += twp[u]; Wg += twg[u];
      if (!wu_[u]) break;
    }
    if (open) { Cp += Wp; Cg += Wg; }
  }

  // lane-63 rule neighbor: LDS handoff from next wave (block-last: own loads)
  if (is63) {
    float a0, a1; int t0;
    if (tid == TPB - 1) { a0 = nb_dp; a1 = nb_dp1; t0 = nb_tk; }
    else                { a0 = ndp0[wid + 1]; a1 = ndp1[wid + 1]; t0 = ntk[wid + 1]; }
    float ng, ns_;
    rule_eval2(a0, a1, t0, base + EPT < Tn - 1, ng, ns_);
    dpn3 = a0; ggn = ng;
  }
  rule_eval2(dp4.w, dpn3, tk4.w, base + 3 < Tn - 1, gg3, sa3);

  // pdur + rules losses (log2-space)
  const float dpx[4] = {dp4.x, dp4.y, dp4.z, dp4.w};
  const float dgl[4] = {g0, g1_, g2_, g3_};
  const float sav[4] = {sa0, sa1, sa2, sa3};
  const float addv[4] = {gg1, gg2, gg3, (base + 3 < Tn - 1) ? ggn : 0.f};
  float pdur_s = 0.f, rules_s = 0.f;
  #pragma unroll
  for (int j = 0; j < 4; ++j) {
    float dp = dpx[j];
    float dr = dp - sav[j] + addv[j];
    float lp = __log2f(dp + 1.f);
    float dlr = lp - __log2f(dr + 1.f);
    rules_s += dlr * dlr;
    float dlg = lp - __log2f(dgl[j] + 1.f);
    pdur_s += dlg * dlg;
  }

  // run-compress with carry; owner thread finalizes each completed word
  const int wf = smeta[0], wl = smeta[1];
  const int nk_true = is63 ? ((tid == TPB - 1) ? -1 : hk[wid + 1]) : nk0;
  float wd_s = 0.f;
  {
    const int   kk[4] = {k0, k1, k2, k3};
    const float pp[4] = {p0, p1, p2, p3};
    const float gg[4] = {g0, g1_, g2_, g3_};
    int cur = k0; float ap = Cp, ag = Cg;
    #pragma unroll
    for (int j = 0; j < 4; ++j) {
      if (kk[j] != cur) {
        if (cur == wl)      { bnd[2] = ap; bnd[3] = ag; }   // unique writer
        else if (cur == wf) { bnd[0] = ap; bnd[1] = ag; }   // unique writer
        else { float d = __log2f(ap + 1.f) - __log2f(ag + 1.f); wd_s += d * d; }
        cur = kk[j]; ap = 0.f; ag = 0.f;
      }
      ap += pp[j]; ag += gg[j];
    }
    if (nk_true != cur) {            // run ends at my last element -> I own it
      if (cur == wl)      { bnd[2] = ap; bnd[3] = ag; }
      else if (cur == wf) { bnd[0] = ap; bnd[1] = ag; }
      else { float d = __log2f(ap + 1.f) - __log2f(ag + 1.f); wd_s += d * d; }
    }
  }

  // single weighted reduction (weights carry the ln2^2 factor)
  float x = (0.6f * LN2S) * pdur_s + (0.3f * LN2S) * rules_s + (WDC * LN2S) * wd_s;
  x = wave_reduce(x);
  if (lane == 0) red[wid][0] = x;
  if (is63) { red[wid][1] = Pp; red[wid][2] = Pg; }
  __syncthreads();

  if (tid == 0) {
    float xs = 0.f, sp = 0.f, sg = 0.f;
    #pragma unroll
    for (int w = 0; w < NW; ++w) { xs += red[w][0]; sp += red[w][1]; sg += red[w][2]; }
    float4 a, b, c;
    a.x = xs; a.y = sp; a.z = sg; a.w = 0.f;
    const bool single = (wf == wl);
    b.x = bnd[0]; b.y = bnd[1]; b.z = __int_as_float(single ? -1 : wf); b.w = 0.f;
    c.x = bnd[2]; c.y = bnd[3]; c.z = __int_as_float(wl); c.w = 0.f;
    const size_t idx = (size_t)blockIdx.x * 3;
    partials[idx]     = a;
    partials[idx + 1] = b;
    partials[idx + 2] = c;
  }
}

// Stage 1 of the epilogue: one thread per row, 16 blocks x 64 threads spread
// across 16 CUs (the single-CU 1024-thread finalize was ~15-20 us; this is the
// same per-row work at 16-way CU parallelism). Writes one double per row.
__global__ __launch_bounds__(64) void fold_kernel(
    const float4* __restrict__ partials, double* __restrict__ rowc)
{
  const int r = blockIdx.x * 64 + threadIdx.x;   // 16*64 == Bn
  float4 A[BPR], Bv[BPR], Cv[BPR];
  #pragma unroll
  for (int j = 0; j < BPR; ++j) {
    const size_t idx = ((size_t)r * BPR + j) * 3;
    A[j]  = partials[idx];
    Bv[j] = partials[idx + 1];
    Cv[j] = partials[idx + 2];
  }

  double xs = 0.0, wdb = 0.0;
  float sp = 0.f, sg = 0.f;
  int curid = -1; float cp = 0.f, cg = 0.f;
  #pragma unroll
  for (int j = 0; j < BPR; ++j) {
    xs += (double)A[j].x; sp += A[j].y; sg += A[j].z;
    const int wfi = __float_as_int(Bv[j].z);
    const int wla = __float_as_int(Cv[j].z);
    if (wfi >= 0) {
      if (wfi != curid) {
        if (curid > 0) { float d = __log2f(cp + 1.f) - __log2f(cg + 1.f); wdb += (double)(d * d); }
        curid = wfi; cp = 0.f; cg = 0.f;
      }
      cp += Bv[j].x; cg += Bv[j].y;
    }
    if (wla >= 0) {
      if (wla != curid) {
        if (curid > 0) { float d = __log2f(cp + 1.f) - __log2f(cg + 1.f); wdb += (double)(d * d); }
        curid = wla; cp = 0.f; cg = 0.f;
      }
      cp += Cv[j].x; cg += Cv[j].y;
    }
  }
  if (curid > 0) { float d = __log2f(cp + 1.f) - __log2f(cg + 1.f); wdb += (double)(d * d); }

  float ds = __log2f(sp + 1.f) - __log2f(sg + 1.f);
  rowc[r] = xs / ((double)Bn * (double)Tn)
          + (0.3 * (double)LN2S) * wdb / ((double)Bn * (double)(Wn - 1))
          + (0.1 * (double)LN2S) * (double)(ds * ds) / (double)Bn;
}

// Stage 2: reduce 1024 row doubles -> out[0].
__global__ __launch_bounds__(1024) void reduce_kernel(
    const double* __restrict__ rowc, float* __restrict__ out)
{
  __shared__ double wsum[16];
  double v = rowc[threadIdx.x];
  #pragma unroll
  for (int o = 32; o > 0; o >>= 1) v += __shfl_down(v, o, 64);
  if ((threadIdx.x & 63) == 0) wsum[threadIdx.x >> 6] = v;
  __syncthreads();
  if (threadIdx.x == 0) {
    double t = 0.0;
    #pragma unroll
    for (int i = 0; i < 16; ++i) t += wsum[i];
    out[0] = (float)t;
  }
}

extern "C" void kernel_launch(void* const* d_in, const int* in_sizes, int n_in,
                              void* d_out, int out_size, void* d_ws, size_t ws_size,
                              hipStream_t stream) {
  const float* dur_pred = (const float*)d_in[0];
  const float* dur_gt   = (const float*)d_in[1];
  const int*   ph2word  = (const int*)d_in[2];
  const int*   txt      = (const int*)d_in[3];

  // workspace: [partials: 8192*48 B = 384 KB][rowc: 1024*8 B], all overwritten
  float4* partials = (float4*)d_ws;
  double* rowc = (double*)((char*)d_ws + (size_t)(Bn * BPR) * 48);

  loss_kernel<<<Bn * BPR, TPB, 0, stream>>>(dur_pred, dur_gt, ph2word, txt, partials);
  fold_kernel<<<Bn / 64, 64, 0, stream>>>(partials, rowc);
  reduce_kernel<<<1, 1024, 0, stream>>>(rowc, (float*)d_out);
}